// Round 1
// baseline (53.548 us; speedup 1.0000x reference)
//
#include <hip/hip_runtime.h>
#include <math.h>

#define B_ 32
#define N_ 256
#define T_OBS_ 50
#define T_S_ 25
#define D_ 128
#define D_H_ 256
#define P_ 8
#define R_ 4  // rows per block in MLP kernel

static constexpr float TWO_PI_F = 6.283185307179586f;
static constexpr double TWO_PI_D = 6.283185307179586476925286766559;
static constexpr float EPS_F = 1e-4f;

// ---------------------------------------------------------------------------
// K1: fnmax[b,t,d] = max over n of f_ego[b,t,d] * f_nei[b,n,t,d]
// 800 blocks (b*25+t) x 512 threads. thread: d4 = tid&31 (float4 over D=128),
// ng = tid>>5 (16 n-groups). Each thread max-reduces 16 n values, then LDS
// combine across the 16 groups.
// ---------------------------------------------------------------------------
__global__ __launch_bounds__(512) void k1_maxreduce(
    const float* __restrict__ f_ego, const float* __restrict__ f_nei,
    float* __restrict__ fnmax) {
  int bt = blockIdx.x;
  int b = bt / T_S_;
  int t = bt - b * T_S_;
  int tid = threadIdx.x;
  int d4 = tid & 31;
  int ng = tid >> 5;  // 0..15

  const float4 e = *(const float4*)(f_ego + (size_t)(b * T_S_ + t) * D_ + 4 * d4);
  float4 m = make_float4(-3.402823466e38f, -3.402823466e38f,
                         -3.402823466e38f, -3.402823466e38f);
  const float* base = f_nei + ((size_t)(b * N_) * T_S_ + t) * D_ + 4 * d4;

#pragma unroll
  for (int i = 0; i < 16; ++i) {
    int n = ng + (i << 4);
    float4 v = *(const float4*)(base + (size_t)n * (T_S_ * D_));
    m.x = fmaxf(m.x, e.x * v.x);
    m.y = fmaxf(m.y, e.y * v.y);
    m.z = fmaxf(m.z, e.z * v.z);
    m.w = fmaxf(m.w, e.w * v.w);
  }

  __shared__ float4 part[16][32];
  part[ng][d4] = m;
  __syncthreads();

  if (tid < 32) {
    float4 r = part[0][tid];
#pragma unroll
    for (int g = 1; g < 16; ++g) {
      float4 v = part[g][tid];
      r.x = fmaxf(r.x, v.x);
      r.y = fmaxf(r.y, v.y);
      r.z = fmaxf(r.z, v.z);
      r.w = fmaxf(r.w, v.w);
    }
    *(float4*)(fnmax + (size_t)(b * T_S_ + t) * D_ + 4 * tid) = r;
  }
}

// ---------------------------------------------------------------------------
// K2: 3-layer MLP on 800 rows. 200 blocks x 256 threads, R_=4 rows/block.
// f3[row][0..63] = relu(relu(relu(in@W1+b1)@W2+b2)@W3+b3)
// ---------------------------------------------------------------------------
__global__ __launch_bounds__(256) void k2_mlp(
    const float* __restrict__ fnmax, const float* __restrict__ W1,
    const float* __restrict__ b1, const float* __restrict__ W2,
    const float* __restrict__ b2, const float* __restrict__ W3,
    const float* __restrict__ b3, float* __restrict__ f3) {
  __shared__ float sin_[R_][D_];
  __shared__ float sh1[R_][D_H_];
  __shared__ float sh2[R_][D_H_];
  int row0 = blockIdx.x * R_;
  int tid = threadIdx.x;

  for (int i = tid; i < R_ * D_; i += 256)
    sin_[i / D_][i % D_] = fnmax[(size_t)row0 * D_ + i];
  __syncthreads();

  {  // layer 1: D_ -> D_H_
    float acc[R_];
    float bb = b1[tid];
#pragma unroll
    for (int r = 0; r < R_; ++r) acc[r] = bb;
    for (int k = 0; k < D_; ++k) {
      float w = W1[(size_t)k * D_H_ + tid];
#pragma unroll
      for (int r = 0; r < R_; ++r) acc[r] = fmaf(sin_[r][k], w, acc[r]);
    }
#pragma unroll
    for (int r = 0; r < R_; ++r) sh1[r][tid] = fmaxf(acc[r], 0.f);
  }
  __syncthreads();

  {  // layer 2: D_H_ -> D_H_
    float acc[R_];
    float bb = b2[tid];
#pragma unroll
    for (int r = 0; r < R_; ++r) acc[r] = bb;
    for (int k = 0; k < D_H_; ++k) {
      float w = W2[(size_t)k * D_H_ + tid];
#pragma unroll
      for (int r = 0; r < R_; ++r) acc[r] = fmaf(sh1[r][k], w, acc[r]);
    }
#pragma unroll
    for (int r = 0; r < R_; ++r) sh2[r][tid] = fmaxf(acc[r], 0.f);
  }
  __syncthreads();

  {  // layer 3: D_H_ -> 64
    int j = tid & 63;
    int r = tid >> 6;  // 0..3
    float acc = b3[j];
    for (int k = 0; k < D_H_; ++k)
      acc = fmaf(sh2[r][k], W3[(size_t)k * 64 + j], acc);
    f3[(size_t)(row0 + r) * 64 + j] = fmaxf(acc, 0.f);
  }
}

// ---------------------------------------------------------------------------
// K3: polar histogram stats over N per (b,t) + final output assembly.
// 800 blocks x 256 threads (one thread per neighbor n).
// out[b,t,p,0:64]  = f3[b,t,:] * counts/(counts+eps)
// out[b,t,p,64:128]= relu(dist_mean*Wce[0,:] + ang_mean*Wce[1,:] + bce)
// ---------------------------------------------------------------------------
__global__ __launch_bounds__(256) void k3_stats_out(
    const float* __restrict__ x_ego, const float* __restrict__ x_nei,
    const float* __restrict__ f3, const float* __restrict__ Wce,
    const float* __restrict__ bce, float* __restrict__ out) {
  int bt = blockIdx.x;
  int b = bt / T_S_;
  int t = bt - b * T_S_;
  int tid = threadIdx.x;

  __shared__ float cnt[P_], dsum[P_], asum[P_];
  if (tid < P_) {
    cnt[tid] = 0.f;
    dsum[tid] = 0.f;
    asum[tid] = 0.f;
  }
  __syncthreads();

  {
    int n = tid;  // 0..255
    int tobs = 2 * t;
    float ex = x_ego[(size_t)(b * T_OBS_ + tobs) * 2 + 0];
    float ey = x_ego[(size_t)(b * T_OBS_ + tobs) * 2 + 1];
    const float* xn = x_nei + ((size_t)(b * N_ + n) * T_OBS_ + tobs) * 2;
    float p0 = xn[0] - ex;
    float p1 = xn[1] - ey;
    float dist = sqrtf(p0 * p0 + p1 * p1);
    double angd = atan2((double)p0, (double)p1);
    if (angd < 0.0) angd += TWO_PI_D;
    float ang = (float)angd;
    int pidx = (int)(angd / (TWO_PI_D / (double)P_));
    bool mask = ((fabsf(p0) + fabsf(p1)) != 0.f) && (dist > 0.005f);
    if (mask && pidx >= 0 && pidx < P_) {
      atomicAdd(&cnt[pidx], 1.f);
      atomicAdd(&dsum[pidx], dist);
      atomicAdd(&asum[pidx], ang);
    }
  }
  __syncthreads();

  const float* f3row = f3 + (size_t)(b * T_S_ + t) * 64;
  float* orow = out + (size_t)(b * T_S_ + t) * (P_ * D_);
#pragma unroll
  for (int ii = 0; ii < 4; ++ii) {
    int i = tid + ii * 256;
    int p = i >> 7;
    int c = i & 127;
    float nn = cnt[p] + EPS_F;
    float val;
    if (c < 64) {
      val = f3row[c] * (cnt[p] / nn);
    } else {
      int j = c - 64;
      float dm = dsum[p] / nn;
      float am = asum[p] / nn;
      val = fmaf(dm, Wce[j], fmaf(am, Wce[64 + j], bce[j]));
      val = fmaxf(val, 0.f);
    }
    orow[i] = val;
  }
}

// ---------------------------------------------------------------------------
extern "C" void kernel_launch(void* const* d_in, const int* in_sizes, int n_in,
                              void* d_out, int out_size, void* d_ws,
                              size_t ws_size, hipStream_t stream) {
  const float* x_ego = (const float*)d_in[0];   // (32,50,2)
  const float* x_nei = (const float*)d_in[1];   // (32,256,50,2)
  const float* f_ego = (const float*)d_in[2];   // (32,25,128)
  const float* f_nei = (const float*)d_in[3];   // (32,256,25,128)
  const float* W1 = (const float*)d_in[4];      // (128,256)
  const float* b1 = (const float*)d_in[5];
  const float* W2 = (const float*)d_in[6];      // (256,256)
  const float* b2 = (const float*)d_in[7];
  const float* W3 = (const float*)d_in[8];      // (256,64)
  const float* b3 = (const float*)d_in[9];
  const float* Wce = (const float*)d_in[10];    // (2,64)
  const float* bce = (const float*)d_in[11];
  float* out = (float*)d_out;                   // (32,25,8,128)

  float* fnmax = (float*)d_ws;                              // 800*128 floats
  float* f3 = (float*)((char*)d_ws + (size_t)B_ * T_S_ * D_ * sizeof(float));

  k1_maxreduce<<<B_ * T_S_, 512, 0, stream>>>(f_ego, f_nei, fnmax);
  k2_mlp<<<(B_ * T_S_) / R_, 256, 0, stream>>>(fnmax, W1, b1, W2, b2, W3, b3,
                                               f3);
  k3_stats_out<<<B_ * T_S_, 256, 0, stream>>>(x_ego, x_nei, f3, Wce, bce, out);
}

// Round 2
// 42.227 us; speedup vs baseline: 1.2681x; 1.2681x over previous
//
#include <hip/hip_runtime.h>
#include <math.h>
#include <float.h>

#define B_ 32
#define N_ 256
#define T_OBS_ 50
#define T_S_ 25
#define D_ 128
#define D_H_ 256
#define P_ 8
#define R_ 4            // rows per block in fused kernel
#define NCH_ 8          // n-chunks in K1
#define NPC_ (N_ / NCH_)      // 32 n per chunk
#define PLANE_ (T_S_ * D_)    // 3200 floats per (b,n)

static constexpr double TWO_PI_D = 6.283185307179586476925286766559;
static constexpr float EPS_F = 1e-4f;

// ---------------------------------------------------------------------------
// K1: partial max over an n-chunk, fully contiguous streaming.
// grid = 32 b * 8 chunks = 256 blocks (1 per CU). 800 threads; thread owns one
// float4 of the (t,d) plane (3200 floats). Per n-iteration the block reads a
// contiguous 12.8 KB; per block a contiguous 409.6 KB of f_nei.
// part[b][c][t*128+d] = max over n in chunk c of e[t,d]*f_nei[b,n,t,d]
// ---------------------------------------------------------------------------
__global__ __launch_bounds__(800) void k1_partial(
    const float* __restrict__ f_ego, const float* __restrict__ f_nei,
    float* __restrict__ part) {
  int b = blockIdx.x >> 3;
  int c = blockIdx.x & 7;
  int tid = threadIdx.x;  // 0..799
  int t = tid >> 5;
  int d4 = tid & 31;

  const float4 e =
      *(const float4*)(f_ego + ((size_t)b * T_S_ + t) * D_ + 4 * d4);
  const float* base =
      f_nei + ((size_t)b * N_ + (size_t)c * NPC_) * PLANE_ + 4 * tid;

  float4 m = make_float4(-FLT_MAX, -FLT_MAX, -FLT_MAX, -FLT_MAX);
#pragma unroll 8
  for (int i = 0; i < NPC_; ++i) {
    float4 v = *(const float4*)(base + (size_t)i * PLANE_);
    m.x = fmaxf(m.x, e.x * v.x);
    m.y = fmaxf(m.y, e.y * v.y);
    m.z = fmaxf(m.z, e.z * v.z);
    m.w = fmaxf(m.w, e.w * v.w);
  }
  *(float4*)(part + (size_t)blockIdx.x * PLANE_ + 4 * tid) = m;
}

// ---------------------------------------------------------------------------
// K2: fused combine + MLP (k-split 2-way) + polar histogram + output.
// 200 blocks x 512 threads, R_=4 rows per block.
// ---------------------------------------------------------------------------
__global__ __launch_bounds__(512) void k2_fused(
    const float* __restrict__ part, const float* __restrict__ W1,
    const float* __restrict__ b1, const float* __restrict__ W2,
    const float* __restrict__ b2, const float* __restrict__ W3,
    const float* __restrict__ b3, const float* __restrict__ x_ego,
    const float* __restrict__ x_nei, const float* __restrict__ Wce,
    const float* __restrict__ bce, float* __restrict__ out) {
  __shared__ float sin_[R_][D_];       // 2 KB
  __shared__ float shp[2][R_][D_H_];   // 8 KB (also reused for layer3 partials)
  __shared__ float sh1[R_][D_H_];      // 4 KB
  __shared__ float sh2[R_][D_H_];      // 4 KB
  __shared__ float f3s[R_][64];        // 1 KB
  __shared__ float cnt[R_][P_], dsum[R_][P_], asum[R_][P_];

  int tid = threadIdx.x;
  int row0 = blockIdx.x * R_;

  // zero histogram bins (ordered before atomics by the syncs below)
  if (tid < R_ * P_) {
    ((float*)cnt)[tid] = 0.f;
    ((float*)dsum)[tid] = 0.f;
    ((float*)asum)[tid] = 0.f;
  }

  // ---- combine K1 partials -> sin_ (the fnmax rows for this block) ----
  for (int idx = tid; idx < R_ * D_; idx += 512) {
    int r = idx >> 7, d = idx & 127;
    int row = row0 + r;
    int b = row / T_S_, t = row - b * T_S_;
    const float* p = part + (size_t)b * NCH_ * PLANE_ + t * D_ + d;
    float m = -FLT_MAX;
#pragma unroll
    for (int c = 0; c < NCH_; ++c) m = fmaxf(m, p[(size_t)c * PLANE_]);
    sin_[r][d] = m;
  }
  __syncthreads();

  int h = tid >> 8;   // k-half 0/1
  int j = tid & 255;  // output index 0..255

  // ---- layer 1: 128 -> 256 (k split 64/64) ----
  {
    float acc[R_] = {0.f, 0.f, 0.f, 0.f};
    int k0 = h * 64;
    for (int k = k0; k < k0 + 64; ++k) {
      float w = W1[(size_t)k * D_H_ + j];
#pragma unroll
      for (int r = 0; r < R_; ++r) acc[r] = fmaf(sin_[r][k], w, acc[r]);
    }
#pragma unroll
    for (int r = 0; r < R_; ++r) shp[h][r][j] = acc[r];
  }
  __syncthreads();
  if (tid < 256) {
    float bb = b1[j];
#pragma unroll
    for (int r = 0; r < R_; ++r)
      sh1[r][j] = fmaxf(shp[0][r][j] + shp[1][r][j] + bb, 0.f);
  }
  __syncthreads();

  // ---- layer 2: 256 -> 256 (k split 128/128) ----
  {
    float acc[R_] = {0.f, 0.f, 0.f, 0.f};
    int k0 = h * 128;
    for (int k = k0; k < k0 + 128; ++k) {
      float w = W2[(size_t)k * D_H_ + j];
#pragma unroll
      for (int r = 0; r < R_; ++r) acc[r] = fmaf(sh1[r][k], w, acc[r]);
    }
#pragma unroll
    for (int r = 0; r < R_; ++r) shp[h][r][j] = acc[r];
  }
  __syncthreads();
  if (tid < 256) {
    float bb = b2[j];
#pragma unroll
    for (int r = 0; r < R_; ++r)
      sh2[r][j] = fmaxf(shp[0][r][j] + shp[1][r][j] + bb, 0.f);
  }
  __syncthreads();

  // ---- layer 3: 256 -> 64, 4 rows (k split 128/128) ----
  {
    int idx = tid & 255;
    int r3 = idx >> 6, j3 = idx & 63;
    float acc = 0.f;
    int k0 = h * 128;
    for (int k = k0; k < k0 + 128; ++k)
      acc = fmaf(sh2[r3][k], W3[(size_t)k * 64 + j3], acc);
    ((float*)shp)[h * 1024 + idx] = acc;  // reuse shp
  }
  __syncthreads();
  if (tid < 256) {
    int r3 = tid >> 6, j3 = tid & 63;
    f3s[r3][j3] =
        fmaxf(((float*)shp)[tid] + ((float*)shp)[1024 + tid] + b3[j3], 0.f);
  }

  // ---- polar histogram: rows (rr, rr+2), one thread per neighbor ----
  {
    int n = tid & 255, rr = tid >> 8;
#pragma unroll
    for (int pp = 0; pp < 2; ++pp) {
      int r = rr + 2 * pp;
      int row = row0 + r;
      int b = row / T_S_, t = row - b * T_S_;
      int tobs = 2 * t;
      float ex = x_ego[((size_t)b * T_OBS_ + tobs) * 2 + 0];
      float ey = x_ego[((size_t)b * T_OBS_ + tobs) * 2 + 1];
      const float* xn = x_nei + (((size_t)b * N_ + n) * T_OBS_ + tobs) * 2;
      float p0 = xn[0] - ex;
      float p1 = xn[1] - ey;
      float dist = sqrtf(p0 * p0 + p1 * p1);
      double angd = atan2((double)p0, (double)p1);
      if (angd < 0.0) angd += TWO_PI_D;
      float ang = (float)angd;
      int pidx = (int)(angd / (TWO_PI_D / (double)P_));
      bool mask = ((fabsf(p0) + fabsf(p1)) != 0.f) && (dist > 0.005f);
      if (mask && pidx >= 0 && pidx < P_) {
        atomicAdd(&cnt[r][pidx], 1.f);
        atomicAdd(&dsum[r][pidx], dist);
        atomicAdd(&asum[r][pidx], ang);
      }
    }
  }
  __syncthreads();

  // ---- output: 4 rows x 1024 = 4096 floats ----
  float* orow = out + (size_t)row0 * (P_ * D_);
#pragma unroll
  for (int ii = 0; ii < 8; ++ii) {
    int idx = tid + ii * 512;  // 0..4095
    int r = idx >> 10;
    int i = idx & 1023;
    int p = i >> 7;
    int c = i & 127;
    float nn = cnt[r][p] + EPS_F;
    float val;
    if (c < 64) {
      val = f3s[r][c] * (cnt[r][p] / nn);
    } else {
      int jj = c - 64;
      float dm = dsum[r][p] / nn;
      float am = asum[r][p] / nn;
      val = fmaf(dm, Wce[jj], fmaf(am, Wce[64 + jj], bce[jj]));
      val = fmaxf(val, 0.f);
    }
    orow[idx] = val;
  }
}

// ---------------------------------------------------------------------------
extern "C" void kernel_launch(void* const* d_in, const int* in_sizes, int n_in,
                              void* d_out, int out_size, void* d_ws,
                              size_t ws_size, hipStream_t stream) {
  const float* x_ego = (const float*)d_in[0];   // (32,50,2)
  const float* x_nei = (const float*)d_in[1];   // (32,256,50,2)
  const float* f_ego = (const float*)d_in[2];   // (32,25,128)
  const float* f_nei = (const float*)d_in[3];   // (32,256,25,128)
  const float* W1 = (const float*)d_in[4];      // (128,256)
  const float* b1 = (const float*)d_in[5];
  const float* W2 = (const float*)d_in[6];      // (256,256)
  const float* b2 = (const float*)d_in[7];
  const float* W3 = (const float*)d_in[8];      // (256,64)
  const float* b3 = (const float*)d_in[9];
  const float* Wce = (const float*)d_in[10];    // (2,64)
  const float* bce = (const float*)d_in[11];
  float* out = (float*)d_out;                   // (32,25,8,128)

  float* part = (float*)d_ws;  // 256 * 3200 floats = 3.2 MB

  k1_partial<<<B_ * NCH_, 800, 0, stream>>>(f_ego, f_nei, part);
  k2_fused<<<(B_ * T_S_) / R_, 512, 0, stream>>>(part, W1, b1, W2, b2, W3, b3,
                                                 x_ego, x_nei, Wce, bce, out);
}